// Round 5
// baseline (302.342 us; speedup 1.0000x reference)
//
#include <hip/hip_runtime.h>
#include <stdint.h>

// Problem constants (B=1)
#define L_SEQ 2048
#define DMODEL 1024
#define DI_DIM 2048
#define NSSM 16
#define NPROJ 2080        // DI + 2N
#define NCHUNK 64
#define LCHUNK 32         // NCHUNK*LCHUNK == L_SEQ

typedef __attribute__((ext_vector_type(8))) short bf16x8;
typedef __attribute__((ext_vector_type(8))) unsigned short u16x8;
typedef __attribute__((ext_vector_type(4))) float f32x4;

__device__ __forceinline__ float bf2f(unsigned short u) {
  union { uint32_t u; float f; } v; v.u = (uint32_t)u << 16; return v.f;
}
__device__ __forceinline__ unsigned short f2bf(float f) {
  union { float f; uint32_t u; } v; v.f = f;
  uint32_t u = v.u;
  return (unsigned short)((u + 0x7fffu + ((u >> 16) & 1u)) >> 16);
}
__device__ __forceinline__ void async16(const void* g, void* l) {
  __builtin_amdgcn_global_load_lds(
      (__attribute__((address_space(1))) void*)(g),
      (__attribute__((address_space(3))) void*)(l), 16, 0, 0);
}
// native-op math (libm log1pf/fdiv expand to huge sequences w/o fast-math;
// switching to __logf/__expf/rcp collapsed scan kernels ~3x -- r7 measured)
__device__ __forceinline__ float softplusf(float p) {
  return (p > 20.f) ? p : __logf(1.f + __expf(p));
}
__device__ __forceinline__ float siluf(float x) {
  return x * __builtin_amdgcn_rcpf(1.f + __expf(-x));
}

#define WAITV(N) asm volatile("s_waitcnt vmcnt(" #N ")" ::: "memory")
#define GBAR()                                   \
  {                                              \
    __builtin_amdgcn_s_barrier();                \
    asm volatile("" ::: "memory");               \
  }

// ---------------- fused f32 -> bf16 converts (x, W_in, W_x, W_out) ----------------
#define CVT_N1 524288                    // x:     2048*1024/4
#define CVT_N2 (CVT_N1 + 1048576)        // W_in:  4096*1024/4
#define CVT_N3 (CVT_N2 + 1064960)        // W_x:   2080*2048/4
#define CVT_N4 (CVT_N3 + 524288)         // W_out: 1024*2048/4
__global__ void k_convert4(const float* __restrict__ x, const float* __restrict__ win,
                           const float* __restrict__ wx, const float* __restrict__ wout,
                           unsigned short* __restrict__ xb, unsigned short* __restrict__ winb,
                           unsigned short* __restrict__ wxb, unsigned short* __restrict__ woutb) {
  int i = blockIdx.x * 256 + threadIdx.x;
  const float4* src; unsigned short* dst; int j;
  if (i < CVT_N1)      { src = (const float4*)x;    dst = xb;    j = i; }
  else if (i < CVT_N2) { src = (const float4*)win;  dst = winb;  j = i - CVT_N1; }
  else if (i < CVT_N3) { src = (const float4*)wx;   dst = wxb;   j = i - CVT_N2; }
  else if (i < CVT_N4) { src = (const float4*)wout; dst = woutb; j = i - CVT_N3; }
  else return;
  float4 v = src[j];
  ushort4 o;
  o.x = f2bf(v.x); o.y = f2bf(v.y); o.z = f2bf(v.z); o.w = f2bf(v.w);
  ((ushort4*)dst)[j] = o;
}

__global__ void k_wout_cvt(const float* __restrict__ in, unsigned short* __restrict__ out) {
  int i = blockIdx.x * 256 + threadIdx.x;   // over DMODEL*DI_DIM/4
  float4 v = ((const float4*)in)[i];
  ushort4 o;
  o.x = f2bf(v.x); o.y = f2bf(v.y); o.z = f2bf(v.z); o.w = f2bf(v.w);
  ((ushort4*)out)[i] = o;
}

// =============== GEMM factor ledger (A/B history) ===============
// atomics -40% | uncoalesced staging -60% | TM=32 dilution -25% | row-major
// LDS conflicts -11% | XOR-swizzle: 0 conflicts | ring depth 2/3/4: null (r1)
// | split-K occupancy 2x: null-to-neg (r2) | m-fastest grid: FETCH -44%,
// dur -9% (r3) | 128^2 tile (LDS-density): null-to-neg (r4).
// Conclusion: this 2-phase-class structure is at its shape ceiling (~420 TF
// @N~2048, above the m102 curve's 320). MfmaUtil pinned ~16% = lockstep
// stage/barrier overhead per m233; only the full 8-phase co-design moves it.
// This round: GEMM1/GEMM2 split into 2 half-N launches with DISTINCT names
// (r2: per-CU throughput is occupancy-flat => 2 sequential halves ~ same
// total) so rocprof top-5 reveals the true second-tier dispatches.

#define GSTAGE(BUF, KT)                                                        \
  {                                                                            \
    async16(ap + (KT), &As[BUF][soA]);                                         \
    async16(bp0 + (KT), &Bs[BUF][soB0]);                                       \
    async16(bp1 + (KT), &Bs[BUF][soB1]);                                       \
  }

#define GCOMPUTE(BUF)                                                          \
  {                                                                            \
    bf16x8 af[4], bfv[2];                                                      \
    _Pragma("unroll")                                                          \
    for (int i = 0; i < 4; i++)                                                \
      af[i] = *(const bf16x8*)&As[BUF][i * 512 + ro];                          \
    _Pragma("unroll")                                                          \
    for (int j = 0; j < 2; j++)                                                \
      bfv[j] = *(const bf16x8*)&Bs[BUF][(wave * 2 + j) * 512 + ro];            \
    _Pragma("unroll")                                                          \
    for (int i = 0; i < 4; i++)                                                \
      _Pragma("unroll")                                                        \
      for (int j = 0; j < 2; j++)                                              \
        acc[i][j] = __builtin_amdgcn_mfma_f32_16x16x32_bf16(af[i], bfv[j],     \
                                                        acc[i][j], 0, 0, 0);   \
  }

// nOff: n-tile offset (half-N splitting). 64x128 tile, DEPTH=3 ring, 36KB LDS.
#define DEFINE_GEMM_BT(NAME, OutT)                                             \
__global__ __launch_bounds__(256) void NAME(                                   \
    const unsigned short* __restrict__ A, const unsigned short* __restrict__ B,\
    const float* __restrict__ bias, OutT* __restrict__ C,                      \
    int M, int N, int K, int nOff) {                                           \
  __shared__ unsigned short As[3][64 * 32];                                    \
  __shared__ unsigned short Bs[3][128 * 32];                                   \
  const int tid = threadIdx.x;                                                 \
  const int wave = tid >> 6;                                                   \
  const int lane = tid & 63;                                                   \
  const int m0 = blockIdx.x * 64;   /* m fastest: B n-panel stays L2-hot */    \
  const int n0 = (blockIdx.y + nOff) * 128;                                    \
  const int kLen = K / gridDim.z;                                              \
  const int kLo = blockIdx.z * kLen;                                           \
  const int srow = lane >> 2;                                                  \
  const int scol = ((lane & 3) ^ ((lane >> 3) & 3)) * 8;                       \
  int ar = m0 + wave * 16 + srow;         if (ar > M - 1) ar = M - 1;          \
  int br0 = n0 + wave * 32 + srow;        if (br0 > N - 1) br0 = N - 1;        \
  int br1 = n0 + wave * 32 + 16 + srow;   if (br1 > N - 1) br1 = N - 1;        \
  const unsigned short* ap  = A + (size_t)ar * K + scol + kLo;                 \
  const unsigned short* bp0 = B + (size_t)br0 * K + scol + kLo;                \
  const unsigned short* bp1 = B + (size_t)br1 * K + scol + kLo;                \
  const int soA  = wave * 512;                                                 \
  const int soB0 = (wave * 2) * 512;                                           \
  const int soB1 = (wave * 2 + 1) * 512;                                       \
  const int mrow = lane & 15;                                                  \
  const int swz8 = (((lane >> 4) ^ ((mrow >> 1) & 3)) * 8);                    \
  const int ro = mrow * 32 + swz8;                                             \
  f32x4 acc[4][2];                                                             \
  _Pragma("unroll")                                                            \
  for (int i = 0; i < 4; i++)                                                  \
    _Pragma("unroll")                                                          \
    for (int j = 0; j < 2; j++) acc[i][j] = (f32x4){0.f, 0.f, 0.f, 0.f};       \
  const int niter = kLen / 32;                                                 \
  _Pragma("unroll")                                                            \
  for (int j = 0; j < 2; j++) GSTAGE(j, j * 32)                                \
  int cur = 0, nxt = 2;                                                        \
  for (int t = 0; t < niter - 2; t++) {                                        \
    WAITV(3);                                                                  \
    GBAR()                                                                     \
    GSTAGE(nxt, (t + 2) * 32)                                                  \
    GCOMPUTE(cur)                                                              \
    cur = (cur == 2) ? 0 : cur + 1;                                            \
    nxt = (nxt == 2) ? 0 : nxt + 1;                                            \
  }                                                                            \
  WAITV(3); GBAR()                                                             \
  GCOMPUTE(cur) cur = (cur == 2) ? 0 : cur + 1;                                \
  WAITV(0); GBAR()                                                             \
  GCOMPUTE(cur)                                                                \
  const bool withBias = (gridDim.z == 1);                                      \
  OutT* Cz = C + (size_t)blockIdx.z * ((size_t)M * N);                         \
  _Pragma("unroll")                                                            \
  for (int j = 0; j < 2; j++) {                                                \
    int col = n0 + wave * 32 + j * 16 + (lane & 15);                           \
    if (col < N) {                                                             \
      float bv = withBias ? bias[col] : 0.f;                                   \
      _Pragma("unroll")                                                        \
      for (int i = 0; i < 4; i++) {                                            \
        int rbase = m0 + i * 16 + (lane >> 4) * 4;                             \
        _Pragma("unroll")                                                      \
        for (int r = 0; r < 4; r++) {                                          \
          float v = acc[i][j][r] + bv;                                         \
          if constexpr (sizeof(OutT) == 2)                                     \
            Cz[(size_t)(rbase + r) * N + col] = (OutT)f2bf(v);                 \
          else                                                                 \
            Cz[(size_t)(rbase + r) * N + col] = (OutT)v;                       \
        }                                                                      \
      }                                                                        \
    }                                                                          \
  }                                                                            \
}

DEFINE_GEMM_BT(k_gemm_xr_a, unsigned short)   // GEMM1 cols    0..2047
DEFINE_GEMM_BT(k_gemm_xr_b, unsigned short)   // GEMM1 cols 2048..4095
DEFINE_GEMM_BT(k_gemm_proj_a, float)          // GEMM2 cols    0..1151
DEFINE_GEMM_BT(k_gemm_proj_b, float)          // GEMM2 cols 1152..2079
DEFINE_GEMM_BT(k_gemm_out, float)             // GEMM3 split-K=2 partials

// ---------------- split-K=2 reduce: out = p0 + p1 + bias ----------------
__global__ void k_reduce_out(const float* __restrict__ part, const float* __restrict__ bias,
                             float* __restrict__ out) {
  int i = blockIdx.x * 256 + threadIdx.x;   // float4 index over 2048*1024
  float4 a = ((const float4*)part)[i];
  float4 b = ((const float4*)(part + (size_t)L_SEQ * DMODEL))[i];
  int col = (i * 4) & (DMODEL - 1);
  float4 bb = *(const float4*)&bias[col];
  float4 o;
  o.x = a.x + b.x + bb.x; o.y = a.y + b.y + bb.y;
  o.z = a.z + b.z + bb.z; o.w = a.w + b.w + bb.w;
  ((float4*)out)[i] = o;
}

// ---------------- depthwise causal conv (K=4) + bias + SiLU, x8 vectorized ----------------
__global__ void k_conv_silu(const unsigned short* __restrict__ xr,
                            const float* __restrict__ Wc,
                            const float* __restrict__ bc,
                            unsigned short* __restrict__ xcb) {
  int idx = blockIdx.x * 256 + threadIdx.x;   // over L*DI/8
  int t = idx >> 8;                            // 256 d-groups of 8 per row
  int d8 = (idx & 255) * 8;
  const size_t rs = 2 * DI_DIM;
  u16x8 x0 = (u16x8)(unsigned short)0, x1 = x0, x2 = x0;
  u16x8 x3 = *(const u16x8*)&xr[(size_t)t * rs + d8];
  if (t >= 1) x2 = *(const u16x8*)&xr[(size_t)(t - 1) * rs + d8];
  if (t >= 2) x1 = *(const u16x8*)&xr[(size_t)(t - 2) * rs + d8];
  if (t >= 3) x0 = *(const u16x8*)&xr[(size_t)(t - 3) * rs + d8];
  float4 b0 = *(const float4*)&bc[d8];
  float4 b1 = *(const float4*)&bc[d8 + 4];
  float bb[8] = {b0.x, b0.y, b0.z, b0.w, b1.x, b1.y, b1.z, b1.w};
  u16x8 o;
#pragma unroll
  for (int j = 0; j < 8; j++) {
    float4 wd = *(const float4*)&Wc[(size_t)(d8 + j) * 4];
    float acc = bb[j] + bf2f(x0[j]) * wd.x + bf2f(x1[j]) * wd.y +
                bf2f(x2[j]) * wd.z + bf2f(x3[j]) * wd.w;
    o[j] = f2bf(siluf(acc));
  }
  *(u16x8*)&xcb[(size_t)t * DI_DIM + d8] = o;
}

// ---------------- scan phase A: per-chunk local scan ----------------
// batch-4 software-pipelined loads (scan_b's batch pattern): 4-deep ILP per
// group + next-group prefetch during compute covers the serial-chain latency.
__global__ __launch_bounds__(256) void k_scan_a(
    const float* __restrict__ proj, const unsigned short* __restrict__ xcb,
    const float* __restrict__ A_log,
    float* __restrict__ Sdelta, float* __restrict__ hstate) {
  __shared__ float Bsh[LCHUNK * NSSM];
  const int d = blockIdx.x * 256 + threadIdx.x;
  const int c = blockIdx.y;
  const int t0 = c * LCHUNK;
  for (int i = threadIdx.x; i < LCHUNK * NSSM; i += 256) {
    int t = i >> 4, n = i & 15;
    Bsh[i] = proj[(size_t)(t0 + t) * NPROJ + DI_DIM + n];
  }
  __syncthreads();
  float Ar[NSSM], h[NSSM];
#pragma unroll
  for (int n = 0; n < NSSM; n++) {
    Ar[n] = -__expf(A_log[d * NSSM + n]);
    h[n] = 0.f;
  }
  const float* pp = proj + (size_t)t0 * NPROJ + d;
  const unsigned short* xp = xcb + (size_t)t0 * DI_DIM + d;
  float pb[4]; unsigned short xb4[4];
#pragma unroll
  for (int j = 0; j < 4; j++) {
    pb[j] = pp[(size_t)j * NPROJ];
    xb4[j] = xp[(size_t)j * DI_DIM];
  }
  float sd = 0.f;
  for (int tg = 0; tg < LCHUNK; tg += 4) {
    float pc[4]; unsigned short xc[4];
#pragma unroll
    for (int j = 0; j < 4; j++) { pc[j] = pb[j]; xc[j] = xb4[j]; }
    if (tg + 4 < LCHUNK) {
#pragma unroll
      for (int j = 0; j < 4; j++) {
        pb[j] = pp[(size_t)(tg + 4 + j) * NPROJ];
        xb4[j] = xp[(size_t)(tg + 4 + j) * DI_DIM];
      }
    }
#pragma unroll
    for (int j = 0; j < 4; j++) {
      float delta = softplusf(pc[j]);
      float dx = delta * bf2f(xc[j]);
      sd += delta;
      const int t = tg + j;
#pragma unroll
      for (int n = 0; n < NSSM; n++)
        h[n] = __expf(delta * Ar[n]) * h[n] + dx * Bsh[t * NSSM + n];
    }
  }
  Sdelta[(size_t)c * DI_DIM + d] = sd;
  float4* hp = (float4*)&hstate[((size_t)c * DI_DIM + d) * NSSM];
  hp[0] = (float4){h[0], h[1], h[2], h[3]};
  hp[1] = (float4){h[4], h[5], h[6], h[7]};
  hp[2] = (float4){h[8], h[9], h[10], h[11]};
  hp[3] = (float4){h[12], h[13], h[14], h[15]};
}

// ---------------- scan phase B: combine across chunks (in-place) ----------------
__global__ void k_scan_b(const float* __restrict__ A_log,
                         const float* __restrict__ Sdelta,
                         float* __restrict__ hstate) {
  int tid = blockIdx.x * 256 + threadIdx.x;  // d*16+n
  int d = tid >> 4;
  float A = -__expf(A_log[tid]);
  float carry = 0.f;
  for (int cb = 0; cb < NCHUNK; cb += 8) {
    float v[8], s[8];
#pragma unroll
    for (int j = 0; j < 8; j++) {
      v[j] = hstate[(size_t)(cb + j) * DI_DIM * NSSM + tid];
      s[j] = Sdelta[(size_t)(cb + j) * DI_DIM + d];
    }
#pragma unroll
    for (int j = 0; j < 8; j++) {
      hstate[(size_t)(cb + j) * DI_DIM * NSSM + tid] = carry;
      carry = __expf(A * s[j]) * carry + v[j];
    }
  }
}

// ---------------- scan phase C: replay with h0, produce y*silu(res) ----------------
__global__ __launch_bounds__(256) void k_scan_c(
    const float* __restrict__ proj, const unsigned short* __restrict__ xcb,
    const float* __restrict__ A_log, const float* __restrict__ h0,
    const float* __restrict__ Dvec, const unsigned short* __restrict__ xr,
    unsigned short* __restrict__ ybf) {
  __shared__ float Bsh[LCHUNK * NSSM];
  __shared__ float Csh[LCHUNK * NSSM];
  const int d = blockIdx.x * 256 + threadIdx.x;
  const int c = blockIdx.y;
  const int t0 = c * LCHUNK;
  for (int i = threadIdx.x; i < LCHUNK * NSSM; i += 256) {
    int t = i >> 4, n = i & 15;
    size_t ob = (size_t)(t0 + t) * NPROJ + DI_DIM + n;
    Bsh[i] = proj[ob];
    Csh[i] = proj[ob + NSSM];
  }
  __syncthreads();
  float Ar[NSSM], h[NSSM];
#pragma unroll
  for (int n = 0; n < NSSM; n++)
    Ar[n] = -__expf(A_log[d * NSSM + n]);
  const float4* h0p = (const float4*)&h0[((size_t)c * DI_DIM + d) * NSSM];
  float4 hv0 = h0p[0], hv1 = h0p[1], hv2 = h0p[2], hv3 = h0p[3];
  h[0] = hv0.x; h[1] = hv0.y; h[2] = hv0.z; h[3] = hv0.w;
  h[4] = hv1.x; h[5] = hv1.y; h[6] = hv1.z; h[7] = hv1.w;
  h[8] = hv2.x; h[9] = hv2.y; h[10] = hv2.z; h[11] = hv2.w;
  h[12] = hv3.x; h[13] = hv3.y; h[14] = hv3.z; h[15] = hv3.w;
  float Dd = Dvec[d];
  const float* pp = proj + (size_t)t0 * NPROJ + d;
  const unsigned short* xp = xcb + (size_t)t0 * DI_DIM + d;
  const unsigned short* rp = xr + (size_t)t0 * (2 * DI_DIM) + DI_DIM + d;
  float pb[4]; unsigned short xb4[4], rb[4];
#pragma unroll
  for (int j = 0; j < 4; j++) {
    pb[j] = pp[(size_t)j * NPROJ];
    xb4[j] = xp[(size_t)j * DI_DIM];
    rb[j] = rp[(size_t)j * (2 * DI_DIM)];
  }
  for (int tg = 0; tg < LCHUNK; tg += 4) {
    float pc[4]; unsigned short xc[4], rc[4];
#pragma unroll
    for (int j = 0; j < 4; j++) { pc[j] = pb[j]; xc[j] = xb4[j]; rc[j] = rb[j]; }
    if (tg + 4 < LCHUNK) {
#pragma unroll
      for (int j = 0; j < 4; j++) {
        pb[j] = pp[(size_t)(tg + 4 + j) * NPROJ];
        xb4[j] = xp[(size_t)(tg + 4 + j) * DI_DIM];
        rb[j] = rp[(size_t)(tg + 4 + j) * (2 * DI_DIM)];
      }
    }
#pragma unroll
    for (int j = 0; j < 4; j++) {
      const int t = tg + j;
      float delta = softplusf(pc[j]);
      float xi = bf2f(xc[j]);
      float dx = delta * xi;
      float y = 0.f;
#pragma unroll
      for (int n = 0; n < NSSM; n++) {
        h[n] = __expf(delta * Ar[n]) * h[n] + dx * Bsh[t * NSSM + n];
        y += h[n] * Csh[t * NSSM + n];
      }
      y += xi * Dd;
      y *= siluf(bf2f(rc[j]));
      ybf[(size_t)(t0 + t) * DI_DIM + d] = f2bf(y);
    }
  }
}

extern "C" void kernel_launch(void* const* d_in, const int* in_sizes, int n_in,
                              void* d_out, int out_size, void* d_ws, size_t ws_size,
                              hipStream_t stream) {
  const float* x      = (const float*)d_in[0];
  const float* W_in   = (const float*)d_in[1];
  const float* b_in   = (const float*)d_in[2];
  const float* W_conv = (const float*)d_in[3];
  const float* b_conv = (const float*)d_in[4];
  const float* W_x    = (const float*)d_in[5];
  const float* b_x    = (const float*)d_in[6];
  const float* W_out  = (const float*)d_in[7];
  const float* b_out  = (const float*)d_in[8];
  const float* A_log  = (const float*)d_in[9];
  const float* Dv     = (const float*)d_in[10];
  float* out = (float*)d_out;

  char* ws = (char*)d_ws;
  size_t off = 0;
  auto alloc = [&](size_t bytes) { void* p = ws + off; off += (bytes + 255) & ~(size_t)255; return p; };
  unsigned short* win_bf = (unsigned short*)alloc((size_t)4096 * DMODEL * 2);        // 8.39 MB; reused as ybf
  unsigned short* wx_bf  = (unsigned short*)alloc((size_t)NPROJ * DI_DIM * 2);       // 8.52 MB
  unsigned short* x_bf   = (unsigned short*)alloc((size_t)L_SEQ * DMODEL * 2);       // 4.19 MB; reused as wout_bf (fallback)
  unsigned short* xr_bf  = (unsigned short*)alloc((size_t)L_SEQ * 2 * DI_DIM * 2);   // 16.78 MB
  unsigned short* xcb    = (unsigned short*)alloc((size_t)L_SEQ * DI_DIM * 2);       // 8.39 MB
  float* proj            = (float*)alloc((size_t)L_SEQ * NPROJ * 4);                 // 17.04 MB; reused as GEMM3 partials (16.78 MB)
  float* Sdelta          = (float*)alloc((size_t)NCHUNK * DI_DIM * 4);               // 0.52 MB
  float* hstate          = (float*)alloc((size_t)NCHUNK * DI_DIM * NSSM * 4);        // 8.39 MB
  if (off > ws_size) return;  // proven base budget: 72.2 MB
  unsigned short* ybf     = win_bf;  // dead after GEMM1, reborn as y (scan_c -> GEMM3)
  unsigned short* wout_bf = x_bf;    // fallback slot (x dead after GEMM1)
  float* part             = proj;    // dead after scan_c, reborn as GEMM3 split-K partials (2 x 8.39 MB)

  // W_out bf16 gets its own tail slot when ws allows (it did in r3/r4)
  unsigned short* wout2 = nullptr;
  {
    size_t need = (size_t)DMODEL * DI_DIM * 2;   // 4.19 MB
    if (off + need <= ws_size) wout2 = (unsigned short*)alloc(need);
  }
  if (wout2) {
    k_convert4<<<CVT_N4 / 256, 256, 0, stream>>>(x, W_in, W_x, W_out,
                                                 x_bf, win_bf, wx_bf, wout2);
    wout_bf = wout2;
  } else {
    k_convert4<<<CVT_N3 / 256, 256, 0, stream>>>(x, W_in, W_x, W_out,
                                                 x_bf, win_bf, wx_bf, x_bf /*unused*/);
  }

  // GEMM1: xr = x @ W_in^T + b_in (2048x4096, K=1024), bf16 out, 64x128 tile,
  // two half-N launches (distinct names for rocprof ranking)
  {
    dim3 g(L_SEQ / 64, 16);
    k_gemm_xr_a<<<g, 256, 0, stream>>>(x_bf, win_bf, b_in, xr_bf, L_SEQ, 4096, DMODEL, 0);
    k_gemm_xr_b<<<g, 256, 0, stream>>>(x_bf, win_bf, b_in, xr_bf, L_SEQ, 4096, DMODEL, 16);
  }
  if (!wout2) {
    k_wout_cvt<<<(DMODEL * DI_DIM / 4) / 256, 256, 0, stream>>>(W_out, wout_bf);
  }
  // depthwise conv + SiLU (x8 vectorized)
  k_conv_silu<<<(L_SEQ * DI_DIM / 8) / 256, 256, 0, stream>>>(xr_bf, W_conv, b_conv, xcb);
  // GEMM2: proj = xi @ W_x^T + b_x (2048x2080, K=2048), f32 out, 64x128 tile,
  // two half-N launches (9 + 8 n-tiles)
  {
    dim3 ga(L_SEQ / 64, 9);
    k_gemm_proj_a<<<ga, 256, 0, stream>>>(xcb, wx_bf, b_x, proj, L_SEQ, NPROJ, DI_DIM, 0);
    dim3 gb(L_SEQ / 64, 8);
    k_gemm_proj_b<<<gb, 256, 0, stream>>>(xcb, wx_bf, b_x, proj, L_SEQ, NPROJ, DI_DIM, 9);
  }
  // selective scan (chunked 3-phase, batch-4 pipelined loads)
  {
    dim3 ga(DI_DIM / 256, NCHUNK);
    k_scan_a<<<ga, 256, 0, stream>>>(proj, xcb, A_log, Sdelta, hstate);
    k_scan_b<<<(DI_DIM * NSSM) / 256, 256, 0, stream>>>(A_log, Sdelta, hstate);
    k_scan_c<<<ga, 256, 0, stream>>>(proj, xcb, A_log, hstate, Dv, xr_bf, ybf);
  }
  // GEMM3: 64x128 tile + split-K=2 (512 blocks), partials in proj region,
  // then reduce+bias
  {
    dim3 g(L_SEQ / 64, DMODEL / 128, 2);
    k_gemm_out<<<g, 256, 0, stream>>>(ybf, wout_bf, b_out, part, L_SEQ, DMODEL, DI_DIM, 0);
    k_reduce_out<<<(L_SEQ * DMODEL / 4) / 256, 256, 0, stream>>>(part, b_out, out);
  }
}

// Round 6
// 264.350 us; speedup vs baseline: 1.1437x; 1.1437x over previous
//
#include <hip/hip_runtime.h>
#include <stdint.h>

// Problem constants (B=1)
#define L_SEQ 2048
#define DMODEL 1024
#define DI_DIM 2048
#define NSSM 16
#define NPROJ 2080        // DI + 2N
#define NCHUNK 64
#define LCHUNK 32         // NCHUNK*LCHUNK == L_SEQ
#define NBC 32            // B/C columns (2*NSSM)

typedef __attribute__((ext_vector_type(8))) short bf16x8;
typedef __attribute__((ext_vector_type(8))) unsigned short u16x8;
typedef __attribute__((ext_vector_type(4))) float f32x4;

__device__ __forceinline__ float bf2f(unsigned short u) {
  union { uint32_t u; float f; } v; v.u = (uint32_t)u << 16; return v.f;
}
__device__ __forceinline__ unsigned short f2bf(float f) {
  union { float f; uint32_t u; } v; v.f = f;
  uint32_t u = v.u;
  return (unsigned short)((u + 0x7fffu + ((u >> 16) & 1u)) >> 16);
}
__device__ __forceinline__ void async16(const void* g, void* l) {
  __builtin_amdgcn_global_load_lds(
      (__attribute__((address_space(1))) void*)(g),
      (__attribute__((address_space(3))) void*)(l), 16, 0, 0);
}
// native-op math (libm log1pf/fdiv expand to huge sequences w/o fast-math;
// switching to __logf/__expf/rcp collapsed scan kernels ~3x -- r7 measured)
__device__ __forceinline__ float softplusf(float p) {
  return (p > 20.f) ? p : __logf(1.f + __expf(p));
}
__device__ __forceinline__ float siluf(float x) {
  return x * __builtin_amdgcn_rcpf(1.f + __expf(-x));
}

#define WAITV(N) asm volatile("s_waitcnt vmcnt(" #N ")" ::: "memory")
#define GBAR()                                   \
  {                                              \
    __builtin_amdgcn_s_barrier();                \
    asm volatile("" ::: "memory");               \
  }

// ---------------- fused f32 -> bf16 converts (x, W_in, W_x, W_out) ----------------
// Also writes wbct: transposed/bf16 copy of W_x rows 2048..2079 in
// [dchunk(256)][n(32)][8] layout for coalesced reads in k_conv_silu_bc.
#define CVT_N1 524288                    // x:     2048*1024/4
#define CVT_N2 (CVT_N1 + 1048576)        // W_in:  4096*1024/4
#define CVT_N3 (CVT_N2 + 1064960)        // W_x:   2080*2048/4
#define CVT_N4 (CVT_N3 + 524288)         // W_out: 1024*2048/4
__global__ void k_convert4(const float* __restrict__ x, const float* __restrict__ win,
                           const float* __restrict__ wx, const float* __restrict__ wout,
                           unsigned short* __restrict__ xb, unsigned short* __restrict__ winb,
                           unsigned short* __restrict__ wxb, unsigned short* __restrict__ woutb,
                           unsigned short* __restrict__ wbct) {
  int i = blockIdx.x * 256 + threadIdx.x;
  const float4* src; unsigned short* dst; int j;
  bool isWx = false;
  if (i < CVT_N1)      { src = (const float4*)x;    dst = xb;    j = i; }
  else if (i < CVT_N2) { src = (const float4*)win;  dst = winb;  j = i - CVT_N1; }
  else if (i < CVT_N3) { src = (const float4*)wx;   dst = wxb;   j = i - CVT_N2; isWx = true; }
  else if (i < CVT_N4) { src = (const float4*)wout; dst = woutb; j = i - CVT_N3; }
  else return;
  float4 v = src[j];
  ushort4 o;
  o.x = f2bf(v.x); o.y = f2bf(v.y); o.z = f2bf(v.z); o.w = f2bf(v.w);
  ((ushort4*)dst)[j] = o;
  if (isWx) {
    int r = j >> 9;               // W_x row (512 float4 per row)
    if (r >= DI_DIM) {            // B/C rows -> transposed copy
      int n = r - DI_DIM;         // 0..31
      int d4 = (j & 511) * 4;
      unsigned short ov[4] = {o.x, o.y, o.z, o.w};
#pragma unroll
      for (int k = 0; k < 4; k++) {
        int d = d4 + k;
        wbct[((size_t)(d >> 3) * NBC + n) * 8 + (d & 7)] = ov[k];
      }
    }
  }
}

__global__ void k_wout_cvt(const float* __restrict__ in, unsigned short* __restrict__ out) {
  int i = blockIdx.x * 256 + threadIdx.x;   // over DMODEL*DI_DIM/4
  float4 v = ((const float4*)in)[i];
  ushort4 o;
  o.x = f2bf(v.x); o.y = f2bf(v.y); o.z = f2bf(v.z); o.w = f2bf(v.w);
  ((ushort4*)out)[i] = o;
}

// =============== GEMM factor ledger (A/B history) ===============
// atomics -40% | uncoalesced staging -60% | TM=32 dilution -25% | row-major
// LDS conflicts -11% | XOR-swizzle: 0 conflicts | ring depth 2/3/4: null (r1)
// | split-K occupancy 2x: null-to-neg (r2) | m-fastest grid: FETCH -44%,
// dur -9% (r3) | 128^2 tile: null-to-neg (r4) | half-N split launches:
// -34..40us TOTAL => per-launch gap+tail ~15-20us (r5).
// This round: GEMM2 grid 544 -> 512 blocks (N=2048; B/C cols fused into conv
// kernel). 544 = 2x256+32 => 32 CUs carry 3 blocks = 1.41x makespan; 512 is
// exactly 2.0/CU balanced. Cross-check: GEMM1 (1024 blk, 4.0/CU, same FLOP)
// never appears in top-5 => balanced ~28us.

#define GSTAGE(BUF, KT)                                                        \
  {                                                                            \
    async16(ap + (KT), &As[BUF][soA]);                                         \
    async16(bp0 + (KT), &Bs[BUF][soB0]);                                       \
    async16(bp1 + (KT), &Bs[BUF][soB1]);                                       \
  }

#define GCOMPUTE(BUF)                                                          \
  {                                                                            \
    bf16x8 af[4], bfv[2];                                                      \
    _Pragma("unroll")                                                          \
    for (int i = 0; i < 4; i++)                                                \
      af[i] = *(const bf16x8*)&As[BUF][i * 512 + ro];                          \
    _Pragma("unroll")                                                          \
    for (int j = 0; j < 2; j++)                                                \
      bfv[j] = *(const bf16x8*)&Bs[BUF][(wave * 2 + j) * 512 + ro];            \
    _Pragma("unroll")                                                          \
    for (int i = 0; i < 4; i++)                                                \
      _Pragma("unroll")                                                        \
      for (int j = 0; j < 2; j++)                                              \
        acc[i][j] = __builtin_amdgcn_mfma_f32_16x16x32_bf16(af[i], bfv[j],     \
                                                        acc[i][j], 0, 0, 0);   \
  }

// 64x128 tile, DEPTH=3 ring (36KB LDS), m-fastest grid. ldc decouples the
// C row stride from the compute width N (GEMM2 writes into proj ldc=2080).
#define DEFINE_GEMM_BT(NAME, OutT)                                             \
__global__ __launch_bounds__(256) void NAME(                                   \
    const unsigned short* __restrict__ A, const unsigned short* __restrict__ B,\
    const float* __restrict__ bias, OutT* __restrict__ C,                      \
    int M, int N, int K, int ldc) {                                            \
  __shared__ unsigned short As[3][64 * 32];                                    \
  __shared__ unsigned short Bs[3][128 * 32];                                   \
  const int tid = threadIdx.x;                                                 \
  const int wave = tid >> 6;                                                   \
  const int lane = tid & 63;                                                   \
  const int m0 = blockIdx.x * 64;   /* m fastest: B n-panel stays L2-hot */    \
  const int n0 = blockIdx.y * 128;                                             \
  const int kLen = K / gridDim.z;                                              \
  const int kLo = blockIdx.z * kLen;                                           \
  const int srow = lane >> 2;                                                  \
  const int scol = ((lane & 3) ^ ((lane >> 3) & 3)) * 8;                       \
  int ar = m0 + wave * 16 + srow;         if (ar > M - 1) ar = M - 1;          \
  int br0 = n0 + wave * 32 + srow;        if (br0 > N - 1) br0 = N - 1;        \
  int br1 = n0 + wave * 32 + 16 + srow;   if (br1 > N - 1) br1 = N - 1;        \
  const unsigned short* ap  = A + (size_t)ar * K + scol + kLo;                 \
  const unsigned short* bp0 = B + (size_t)br0 * K + scol + kLo;                \
  const unsigned short* bp1 = B + (size_t)br1 * K + scol + kLo;                \
  const int soA  = wave * 512;                                                 \
  const int soB0 = (wave * 2) * 512;                                           \
  const int soB1 = (wave * 2 + 1) * 512;                                       \
  const int mrow = lane & 15;                                                  \
  const int swz8 = (((lane >> 4) ^ ((mrow >> 1) & 3)) * 8);                    \
  const int ro = mrow * 32 + swz8;                                             \
  f32x4 acc[4][2];                                                             \
  _Pragma("unroll")                                                            \
  for (int i = 0; i < 4; i++)                                                  \
    _Pragma("unroll")                                                          \
    for (int j = 0; j < 2; j++) acc[i][j] = (f32x4){0.f, 0.f, 0.f, 0.f};       \
  const int niter = kLen / 32;                                                 \
  _Pragma("unroll")                                                            \
  for (int j = 0; j < 2; j++) GSTAGE(j, j * 32)                                \
  int cur = 0, nxt = 2;                                                        \
  for (int t = 0; t < niter - 2; t++) {                                        \
    WAITV(3);                                                                  \
    GBAR()                                                                     \
    GSTAGE(nxt, (t + 2) * 32)                                                  \
    GCOMPUTE(cur)                                                              \
    cur = (cur == 2) ? 0 : cur + 1;                                            \
    nxt = (nxt == 2) ? 0 : nxt + 1;                                            \
  }                                                                            \
  WAITV(3); GBAR()                                                             \
  GCOMPUTE(cur) cur = (cur == 2) ? 0 : cur + 1;                                \
  WAITV(0); GBAR()                                                             \
  GCOMPUTE(cur)                                                                \
  const bool withBias = (gridDim.z == 1);                                      \
  OutT* Cz = C + (size_t)blockIdx.z * ((size_t)M * ldc);                       \
  _Pragma("unroll")                                                            \
  for (int j = 0; j < 2; j++) {                                                \
    int col = n0 + wave * 32 + j * 16 + (lane & 15);                           \
    if (col < N) {                                                             \
      float bv = withBias ? bias[col] : 0.f;                                   \
      _Pragma("unroll")                                                        \
      for (int i = 0; i < 4; i++) {                                            \
        int rbase = m0 + i * 16 + (lane >> 4) * 4;                             \
        _Pragma("unroll")                                                      \
        for (int r = 0; r < 4; r++) {                                          \
          float v = acc[i][j][r] + bv;                                         \
          if constexpr (sizeof(OutT) == 2)                                     \
            Cz[(size_t)(rbase + r) * ldc + col] = (OutT)f2bf(v);               \
          else                                                                 \
            Cz[(size_t)(rbase + r) * ldc + col] = (OutT)v;                     \
        }                                                                      \
      }                                                                        \
    }                                                                          \
  }                                                                            \
}

DEFINE_GEMM_BT(k_gemm_xr, unsigned short)   // GEMM1: 32x32 = 1024 blk = 4.0/CU
DEFINE_GEMM_BT(k_gemm_proj, float)          // GEMM2: 32x16 = 512 blk = 2.0/CU
DEFINE_GEMM_BT(k_gemm_out, float)           // GEMM3: 32x8x2 = 512 blk = 2.0/CU

// ---------------- split-K=2 reduce: out = p0 + p1 + bias ----------------
__global__ void k_reduce_out(const float* __restrict__ part, const float* __restrict__ bias,
                             float* __restrict__ out) {
  int i = blockIdx.x * 256 + threadIdx.x;   // float4 index over 2048*1024
  float4 a = ((const float4*)part)[i];
  float4 b = ((const float4*)(part + (size_t)L_SEQ * DMODEL))[i];
  int col = (i * 4) & (DMODEL - 1);
  float4 bb = *(const float4*)&bias[col];
  float4 o;
  o.x = a.x + b.x + bb.x; o.y = a.y + b.y + bb.y;
  o.z = a.z + b.z + bb.z; o.w = a.w + b.w + bb.w;
  ((float4*)out)[i] = o;
}

// ---------------- conv(K=4)+SiLU + fused B/C projection ----------------
// 256 blocks x 8 timesteps. Per t: depthwise conv + SiLU (x8 vectorized,
// sliding window) -> xcb + xi staged in LDS (f32). Then the 32 B/C output
// cols of proj (= xi @ W_x[2048:2080]^T + b_x) are computed here, letting
// GEMM2 shrink to N=2048 = balanced 512-block grid (the whole point).
#define TCONV 8
__global__ __launch_bounds__(256) void k_conv_silu_bc(
    const unsigned short* __restrict__ xr, const float* __restrict__ Wc,
    const float* __restrict__ bc, const unsigned short* __restrict__ wbct,
    const float* __restrict__ bx, unsigned short* __restrict__ xcb,
    float* __restrict__ proj) {
  __shared__ float xi_sh[TCONV][DI_DIM];   // 64 KB
  __shared__ float red[8][TCONV][NBC];     // 8 KB
  const int tid = threadIdx.x;
  const int t0 = blockIdx.x * TCONV;
  const int d8 = tid * 8;
  // conv weights/bias for this thread's 8 channels
  float wd[8][4], bb[8];
#pragma unroll
  for (int j = 0; j < 8; j++) {
    float4 w = *(const float4*)&Wc[(size_t)(d8 + j) * 4];
    wd[j][0] = w.x; wd[j][1] = w.y; wd[j][2] = w.z; wd[j][3] = w.w;
  }
  {
    float4 b0 = *(const float4*)&bc[d8];
    float4 b1 = *(const float4*)&bc[d8 + 4];
    bb[0] = b0.x; bb[1] = b0.y; bb[2] = b0.z; bb[3] = b0.w;
    bb[4] = b1.x; bb[5] = b1.y; bb[6] = b1.z; bb[7] = b1.w;
  }
  const size_t rs = 2 * DI_DIM;
  u16x8 xw0 = (u16x8)(unsigned short)0, xw1 = xw0, xw2 = xw0;
  if (t0 >= 3) xw0 = *(const u16x8*)&xr[(size_t)(t0 - 3) * rs + d8];
  if (t0 >= 2) xw1 = *(const u16x8*)&xr[(size_t)(t0 - 2) * rs + d8];
  if (t0 >= 1) xw2 = *(const u16x8*)&xr[(size_t)(t0 - 1) * rs + d8];
  for (int t = 0; t < TCONV; t++) {
    u16x8 xw3 = *(const u16x8*)&xr[(size_t)(t0 + t) * rs + d8];
    u16x8 o;
#pragma unroll
    for (int j = 0; j < 8; j++) {
      float acc = bb[j] + bf2f(xw0[j]) * wd[j][0] + bf2f(xw1[j]) * wd[j][1] +
                  bf2f(xw2[j]) * wd[j][2] + bf2f(xw3[j]) * wd[j][3];
      unsigned short ob = f2bf(siluf(acc));
      o[j] = ob;
      xi_sh[t][d8 + j] = bf2f(ob);   // match xcb rounding (GEMM2 consistency)
    }
    *(u16x8*)&xcb[(size_t)(t0 + t) * DI_DIM + d8] = o;
    xw0 = xw1; xw1 = xw2; xw2 = xw3;
  }
  __syncthreads();
  // B/C dot: thread (n = tid&31, seg = tid>>5); seg covers 256 d.
  const int n = tid & 31, seg = tid >> 5;
  float acc[TCONV];
#pragma unroll
  for (int t = 0; t < TCONV; t++) acc[t] = 0.f;
  for (int c = 0; c < 32; c++) {
    int dc = seg * 32 + c;                 // global d-chunk (8 d)
    u16x8 w8 = *(const u16x8*)&wbct[((size_t)dc * NBC + n) * 8];
    float wf[8];
#pragma unroll
    for (int j = 0; j < 8; j++) wf[j] = bf2f(w8[j]);
#pragma unroll
    for (int t = 0; t < TCONV; t++) {
      const f32x4* xp = (const f32x4*)&xi_sh[t][dc * 8];
      f32x4 x0 = xp[0], x1 = xp[1];
      acc[t] += x0[0] * wf[0] + x0[1] * wf[1] + x0[2] * wf[2] + x0[3] * wf[3] +
                x1[0] * wf[4] + x1[1] * wf[5] + x1[2] * wf[6] + x1[3] * wf[7];
    }
  }
#pragma unroll
  for (int t = 0; t < TCONV; t++) red[seg][t][n] = acc[t];
  __syncthreads();
  // reduce 8 segs -> 256 outputs (8t x 32n), one per thread, + bias
  {
    int t = tid >> 5, nn = tid & 31;
    float s = 0.f;
#pragma unroll
    for (int w = 0; w < 8; w++) s += red[w][t][nn];
    s += bx[DI_DIM + nn];
    proj[(size_t)(t0 + t) * NPROJ + DI_DIM + nn] = s;
  }
}

// ---------------- scan phase A: per-chunk local scan ----------------
__global__ __launch_bounds__(256) void k_scan_a(
    const float* __restrict__ proj, const unsigned short* __restrict__ xcb,
    const float* __restrict__ A_log,
    float* __restrict__ Sdelta, float* __restrict__ hstate) {
  __shared__ float Bsh[LCHUNK * NSSM];
  const int d = blockIdx.x * 256 + threadIdx.x;
  const int c = blockIdx.y;
  const int t0 = c * LCHUNK;
  for (int i = threadIdx.x; i < LCHUNK * NSSM; i += 256) {
    int t = i >> 4, n = i & 15;
    Bsh[i] = proj[(size_t)(t0 + t) * NPROJ + DI_DIM + n];
  }
  __syncthreads();
  float Ar[NSSM], h[NSSM];
#pragma unroll
  for (int n = 0; n < NSSM; n++) {
    Ar[n] = -__expf(A_log[d * NSSM + n]);
    h[n] = 0.f;
  }
  const float* pp = proj + (size_t)t0 * NPROJ + d;
  const unsigned short* xp = xcb + (size_t)t0 * DI_DIM + d;
  float p_nxt = pp[0];
  unsigned short x_nxt = xp[0];
  float sd = 0.f;
  for (int t = 0; t < LCHUNK; t++) {
    float p = p_nxt;
    unsigned short xu = x_nxt;
    if (t + 1 < LCHUNK) {                          // prefetch next step
      p_nxt = pp[(size_t)(t + 1) * NPROJ];
      x_nxt = xp[(size_t)(t + 1) * DI_DIM];
    }
    float delta = softplusf(p);
    float dx = delta * bf2f(xu);
    sd += delta;
#pragma unroll
    for (int n = 0; n < NSSM; n++)
      h[n] = __expf(delta * Ar[n]) * h[n] + dx * Bsh[t * NSSM + n];
  }
  Sdelta[(size_t)c * DI_DIM + d] = sd;
  float4* hp = (float4*)&hstate[((size_t)c * DI_DIM + d) * NSSM];
  hp[0] = (float4){h[0], h[1], h[2], h[3]};
  hp[1] = (float4){h[4], h[5], h[6], h[7]};
  hp[2] = (float4){h[8], h[9], h[10], h[11]};
  hp[3] = (float4){h[12], h[13], h[14], h[15]};
}

// ---------------- scan phase B: combine across chunks (in-place) ----------------
__global__ void k_scan_b(const float* __restrict__ A_log,
                         const float* __restrict__ Sdelta,
                         float* __restrict__ hstate) {
  int tid = blockIdx.x * 256 + threadIdx.x;  // d*16+n
  int d = tid >> 4;
  float A = -__expf(A_log[tid]);
  float carry = 0.f;
  for (int cb = 0; cb < NCHUNK; cb += 8) {
    float v[8], s[8];
#pragma unroll
    for (int j = 0; j < 8; j++) {
      v[j] = hstate[(size_t)(cb + j) * DI_DIM * NSSM + tid];
      s[j] = Sdelta[(size_t)(cb + j) * DI_DIM + d];
    }
#pragma unroll
    for (int j = 0; j < 8; j++) {
      hstate[(size_t)(cb + j) * DI_DIM * NSSM + tid] = carry;
      carry = __expf(A * s[j]) * carry + v[j];
    }
  }
}

// ---------------- scan phase C: replay with h0, produce y*silu(res) ----------------
__global__ __launch_bounds__(256) void k_scan_c(
    const float* __restrict__ proj, const unsigned short* __restrict__ xcb,
    const float* __restrict__ A_log, const float* __restrict__ h0,
    const float* __restrict__ Dvec, const unsigned short* __restrict__ xr,
    unsigned short* __restrict__ ybf) {
  __shared__ float Bsh[LCHUNK * NSSM];
  __shared__ float Csh[LCHUNK * NSSM];
  const int d = blockIdx.x * 256 + threadIdx.x;
  const int c = blockIdx.y;
  const int t0 = c * LCHUNK;
  for (int i = threadIdx.x; i < LCHUNK * NSSM; i += 256) {
    int t = i >> 4, n = i & 15;
    size_t ob = (size_t)(t0 + t) * NPROJ + DI_DIM + n;
    Bsh[i] = proj[ob];
    Csh[i] = proj[ob + NSSM];
  }
  __syncthreads();
  float Ar[NSSM], h[NSSM];
#pragma unroll
  for (int n = 0; n < NSSM; n++)
    Ar[n] = -__expf(A_log[d * NSSM + n]);
  const float4* h0p = (const float4*)&h0[((size_t)c * DI_DIM + d) * NSSM];
  float4 hv0 = h0p[0], hv1 = h0p[1], hv2 = h0p[2], hv3 = h0p[3];
  h[0] = hv0.x; h[1] = hv0.y; h[2] = hv0.z; h[3] = hv0.w;
  h[4] = hv1.x; h[5] = hv1.y; h[6] = hv1.z; h[7] = hv1.w;
  h[8] = hv2.x; h[9] = hv2.y; h[10] = hv2.z; h[11] = hv2.w;
  h[12] = hv3.x; h[13] = hv3.y; h[14] = hv3.z; h[15] = hv3.w;
  float Dd = Dvec[d];
  const float* pp = proj + (size_t)t0 * NPROJ + d;
  const unsigned short* xp = xcb + (size_t)t0 * DI_DIM + d;
  const unsigned short* rp = xr + (size_t)t0 * (2 * DI_DIM) + DI_DIM + d;
  float p_nxt = pp[0];
  unsigned short x_nxt = xp[0];
  unsigned short r_nxt = rp[0];
  for (int t = 0; t < LCHUNK; t++) {
    float p = p_nxt;
    unsigned short xu = x_nxt, ru = r_nxt;
    if (t + 1 < LCHUNK) {                          // prefetch next step
      p_nxt = pp[(size_t)(t + 1) * NPROJ];
      x_nxt = xp[(size_t)(t + 1) * DI_DIM];
      r_nxt = rp[(size_t)(t + 1) * (2 * DI_DIM)];
    }
    float delta = softplusf(p);
    float xi = bf2f(xu);
    float dx = delta * xi;
    float y = 0.f;
#pragma unroll
    for (int n = 0; n < NSSM; n++) {
      h[n] = __expf(delta * Ar[n]) * h[n] + dx * Bsh[t * NSSM + n];
      y += h[n] * Csh[t * NSSM + n];
    }
    y += xi * Dd;
    y *= siluf(bf2f(ru));
    ybf[(size_t)(t0 + t) * DI_DIM + d] = f2bf(y);
  }
}

extern "C" void kernel_launch(void* const* d_in, const int* in_sizes, int n_in,
                              void* d_out, int out_size, void* d_ws, size_t ws_size,
                              hipStream_t stream) {
  const float* x      = (const float*)d_in[0];
  const float* W_in   = (const float*)d_in[1];
  const float* b_in   = (const float*)d_in[2];
  const float* W_conv = (const float*)d_in[3];
  const float* b_conv = (const float*)d_in[4];
  const float* W_x    = (const float*)d_in[5];
  const float* b_x    = (const float*)d_in[6];
  const float* W_out  = (const float*)d_in[7];
  const float* b_out  = (const float*)d_in[8];
  const float* A_log  = (const float*)d_in[9];
  const float* Dv     = (const float*)d_in[10];
  float* out = (float*)d_out;

  char* ws = (char*)d_ws;
  size_t off = 0;
  auto alloc = [&](size_t bytes) { void* p = ws + off; off += (bytes + 255) & ~(size_t)255; return p; };
  unsigned short* win_bf = (unsigned short*)alloc((size_t)4096 * DMODEL * 2);        // 8.39 MB; reused as ybf
  unsigned short* wx_bf  = (unsigned short*)alloc((size_t)NPROJ * DI_DIM * 2);       // 8.52 MB
  unsigned short* x_bf   = (unsigned short*)alloc((size_t)L_SEQ * DMODEL * 2);       // 4.19 MB; reused as wout_bf (fallback)
  unsigned short* xr_bf  = (unsigned short*)alloc((size_t)L_SEQ * 2 * DI_DIM * 2);   // 16.78 MB
  unsigned short* xcb    = (unsigned short*)alloc((size_t)L_SEQ * DI_DIM * 2);       // 8.39 MB
  float* proj            = (float*)alloc((size_t)L_SEQ * NPROJ * 4);                 // 17.04 MB; reused as GEMM3 partials (16.78 MB)
  float* Sdelta          = (float*)alloc((size_t)NCHUNK * DI_DIM * 4);               // 0.52 MB
  float* hstate          = (float*)alloc((size_t)NCHUNK * DI_DIM * NSSM * 4);        // 8.39 MB
  unsigned short* wbct   = (unsigned short*)alloc((size_t)DI_DIM * NBC * 2);         // 0.13 MB (transposed W_x B/C)
  if (off > ws_size) return;  // base budget ~72.4 MB
  unsigned short* ybf     = win_bf;  // dead after GEMM1, reborn as y (scan_c -> GEMM3)
  unsigned short* wout_bf = x_bf;    // fallback slot (x dead after GEMM1)
  float* part             = proj;    // dead after scan_c, reborn as GEMM3 split-K partials (2 x 8.39 MB)

  // W_out bf16 gets its own tail slot when ws allows (it did in r3-r5)
  unsigned short* wout2 = nullptr;
  {
    size_t need = (size_t)DMODEL * DI_DIM * 2;   // 4.19 MB
    if (off + need <= ws_size) wout2 = (unsigned short*)alloc(need);
  }
  if (wout2) {
    k_convert4<<<CVT_N4 / 256, 256, 0, stream>>>(x, W_in, W_x, W_out,
                                                 x_bf, win_bf, wx_bf, wout2, wbct);
    wout_bf = wout2;
  } else {
    k_convert4<<<CVT_N3 / 256, 256, 0, stream>>>(x, W_in, W_x, W_out,
                                                 x_bf, win_bf, wx_bf, x_bf /*unused*/, wbct);
  }

  // GEMM1: xr = x @ W_in^T + b_in (2048x4096, K=1024), bf16 out
  // grid 32x32 = 1024 blocks = exactly 4.0/CU (balanced)
  {
    dim3 g(L_SEQ / 64, 4096 / 128);
    k_gemm_xr<<<g, 256, 0, stream>>>(x_bf, win_bf, b_in, xr_bf, L_SEQ, 4096, DMODEL, 4096);
  }
  if (!wout2) {
    k_wout_cvt<<<(DMODEL * DI_DIM / 4) / 256, 256, 0, stream>>>(W_out, wout_bf);
  }
  // conv + SiLU + fused B/C projection (writes xcb and proj[:,2048:2080])
  k_conv_silu_bc<<<L_SEQ / TCONV, 256, 0, stream>>>(xr_bf, W_conv, b_conv, wbct,
                                                    b_x, xcb, proj);
  // GEMM2: proj[:, :2048] = xi @ W_x[:2048]^T + b_x (N=2048, K=2048)
  // grid 32x16 = 512 blocks = exactly 2.0/CU (balanced; was 544 = 1.41x tail)
  {
    dim3 g(L_SEQ / 64, 2048 / 128);
    k_gemm_proj<<<g, 256, 0, stream>>>(xcb, wx_bf, b_x, proj, L_SEQ, 2048, DI_DIM, NPROJ);
  }
  // selective scan (chunked 3-phase)
  {
    dim3 ga(DI_DIM / 256, NCHUNK);
    k_scan_a<<<ga, 256, 0, stream>>>(proj, xcb, A_log, Sdelta, hstate);
    k_scan_b<<<(DI_DIM * NSSM) / 256, 256, 0, stream>>>(A_log, Sdelta, hstate);
    k_scan_c<<<ga, 256, 0, stream>>>(proj, xcb, A_log, hstate, Dv, xr_bf, ybf);
  }
  // GEMM3: split-K=2 (512 blocks = 2.0/CU), partials in proj region, then reduce+bias
  {
    dim3 g(L_SEQ / 64, DMODEL / 128, 2);
    k_gemm_out<<<g, 256, 0, stream>>>(ybf, wout_bf, b_out, part, L_SEQ, DMODEL, DI_DIM, DMODEL);
    k_reduce_out<<<(L_SEQ * DMODEL / 4) / 256, 256, 0, stream>>>(part, b_out, out);
  }
}